// Round 4
// baseline (437.997 us; speedup 1.0000x reference)
//
#include <hip/hip_runtime.h>
#include <hip/hip_bf16.h>
#include <math.h>

// Sizes (fixed): BATCH=2, SEQ=2048, DIM=768, HEADS=8, DK=DV=64, F=192, d_inner=512
// All internal compute in fp16 storage + fp32 MFMA accumulation.

typedef _Float16 f16x8 __attribute__((ext_vector_type(8)));
typedef _Float16 f16x4 __attribute__((ext_vector_type(4)));
typedef float f32x4 __attribute__((ext_vector_type(4)));

#define MFMA16(a, b, c) __builtin_amdgcn_mfma_f32_16x16x32_f16((a), (b), (c), 0, 0, 0)

// ---------------- f32 -> fp16 elementwise (vectorized x4) ----------------
__global__ __launch_bounds__(256) void cvt4_kernel(const float* __restrict__ in,
                                                   _Float16* __restrict__ out, int n4) {
  int idx = blockIdx.x * 256 + threadIdx.x;
  if (idx < n4) {
    float4 v = ((const float4*)in)[idx];
    f16x4 o;
    o[0] = (_Float16)v.x; o[1] = (_Float16)v.y; o[2] = (_Float16)v.z; o[3] = (_Float16)v.w;
    ((f16x4*)out)[idx] = o;
  }
}

// ---------------- f32 [K][N] -> fp16 transposed [N][K] ----------------
__global__ __launch_bounds__(256) void cvt_t_kernel(const float* __restrict__ in,
                                                    _Float16* __restrict__ out, int K, int N) {
  int idx = blockIdx.x * 256 + threadIdx.x;
  if (idx < K * N) {
    int k = idx / N, c = idx % N;
    out[(size_t)c * K + k] = (_Float16)in[idx];
  }
}

// ---- three [768][512] f32 weights -> one fp16 transposed [1536][768] ----
__global__ __launch_bounds__(256) void cvt_t3_kernel(const float* __restrict__ Wq,
                                                     const float* __restrict__ Wk,
                                                     const float* __restrict__ Wv,
                                                     _Float16* __restrict__ out) {
  int idx = blockIdx.x * 256 + threadIdx.x;  // over 3*768*512
  const int per = 768 * 512;
  int sel = idx / per, rem = idx - sel * per;
  int k = rem / 512, c = rem % 512;
  const float* W = (sel == 0) ? Wq : (sel == 1) ? Wk : Wv;
  out[((size_t)sel * 512 + c) * 768 + k] = (_Float16)W[rem];
}

// ---- gamma-basis row-invariant constants: lnrm[i] = lgamma(conc) - conc*log(rate) ----
__global__ __launch_bounds__(64) void pos_const_kernel(float* __restrict__ lnrm) {
  int t = threadIdx.x;
  if (t < 32) {
    float mean = 64.f * (float)(t + 1);
    float sd = 32.f;
    float conc = (mean / sd) * (mean / sd);
    float rate = mean / (sd * sd);
    lnrm[t] = lgammaf(conc) - conc * logf(rate);
  }
}

// ---------------- positional embedding: posb [4096][192] fp16 ----------------
// row r: distance = r - 2047. cols 0..31 exp basis, 32..63 center mask,
// 64..95 gamma pdf (row-max normalized), 96..191 = sign * cols 0..95.
// row 4095 = zeros (pad; produces relk row 4095 = 0, computed-but-unread).
__global__ __launch_bounds__(128) void pos_embed_kernel(_Float16* __restrict__ posb,
                                                        const float* __restrict__ lnrm) {
  __shared__ float sg[32];
  const int r = blockIdx.x, t = threadIdx.x;
  if (r >= 4095) {
    if (t < 96) {
      posb[(size_t)r * 192 + t] = (_Float16)0.f;
      posb[(size_t)r * 192 + 96 + t] = (_Float16)0.f;
    }
    return;
  }
  const float dist = (float)(r - 2047);
  const float absd = fabsf(dist);
  const float sgn = (dist > 0.f) ? 1.f : ((dist < 0.f) ? -1.f : 0.f);
  float val = 0.f;
  if (t < 32) {
    float e = 3.f + (float)t * (8.f / 31.f);
    float hl = exp2f(e);
    val = exp2f(-absd / hl);
  } else if (t < 64) {
    int i = t - 32;
    float cw = exp2f((float)(i + 1)) - 1.f;
    val = (cw > absd) ? 1.f : 0.f;
  } else if (t < 96) {
    int i = t - 64;
    float mean = 64.f * (float)(i + 1);
    float sd = 32.f;
    float conc = (mean / sd) * (mean / sd);
    float rate = mean / (sd * sd);
    float lu = (conc - 1.f) * logf(absd) - rate * absd;
    val = expf(lu - lnrm[i]) + 1e-8f;
    sg[i] = val;
  }
  __syncthreads();
  if (t >= 64 && t < 96) {
    float mx = sg[0];
#pragma unroll
    for (int i = 1; i < 32; ++i) mx = fmaxf(mx, sg[i]);
    val = val / mx;
  }
  if (t < 96) {
    posb[(size_t)r * 192 + t] = (_Float16)val;
    posb[(size_t)r * 192 + 96 + t] = (_Float16)(sgn * val);
  }
}

// ---------------- fused QKV projection: [4096][768] x [1536][768]^T ----------------
// grid (24, 64), 256 thr = 4 waves; tile 64x64; col 0..511 -> q, 512..1023 -> k, 1024..1535 -> v.
__global__ __launch_bounds__(256) void gemm_qkv(
    const _Float16* __restrict__ A, const _Float16* __restrict__ Bt,
    _Float16* __restrict__ qc, _Float16* __restrict__ qp,
    _Float16* __restrict__ kb, _Float16* __restrict__ vt,
    const float* __restrict__ bc, const float* __restrict__ bp) {
  const int tid = threadIdx.x;
  const int w = tid >> 6, lane = tid & 63, g = lane >> 4, m = lane & 15;
  const int row0 = blockIdx.y * 64 + w * 16;
  const int c0 = blockIdx.x * 64;
  f32x4 acc[4] = {};
  const _Float16* Ap = A + (size_t)(row0 + m) * 768 + g * 8;
  const _Float16* Bp = Bt + (size_t)(c0 + m) * 768 + g * 8;
  for (int k0 = 0; k0 < 768; k0 += 32) {
    f16x8 a = *(const f16x8*)(Ap + k0);
#pragma unroll
    for (int cf = 0; cf < 4; ++cf) {
      f16x8 bfr = *(const f16x8*)(Bp + (size_t)cf * 16 * 768 + k0);
      acc[cf] = MFMA16(a, bfr, acc[cf]);
    }
  }
  const int proj = c0 >> 9;  // uniform per block
#pragma unroll
  for (int cf = 0; cf < 4; ++cf) {
    const int col = c0 + cf * 16 + m;
    const int c = col & 511, hh = c >> 6, dk = c & 63;
    float b0 = 0.f, b1 = 0.f;
    if (proj == 0) { b0 = bc[c]; b1 = bp[c]; }
#pragma unroll
    for (int r = 0; r < 4; ++r) {
      const int row = row0 + g * 4 + r;
      const int bb = row >> 11, n = row & 2047;
      const float v = acc[cf][r];
      if (proj == 0) {
        const size_t ad = ((size_t)(bb * 8 + hh) * 2048 + n) * 64 + dk;
        const float vs = v * 0.125f;  // DIM_KEY^-0.5
        qc[ad] = (_Float16)(vs + b0);
        qp[ad] = (_Float16)(vs + b1);
      } else if (proj == 1) {
        kb[((size_t)(bb * 8 + hh) * 2048 + n) * 64 + dk] = (_Float16)v;
      } else {
        vt[((size_t)(bb * 8 + hh) * 64 + dk) * 2048 + n] = (_Float16)v;
      }
    }
  }
}

// ---------------- generic MFMA GEMM: C[M][*] = A[M][K] * Bt[N][K]^T ----------------
// MODE 3: relk -> fp16 [h][4096][64]; MODE 4: out-proj -> f32 [row][N] + bias0[col]
template <int MODE>
__global__ __launch_bounds__(256) void gemm_bt(
    const _Float16* __restrict__ A, const _Float16* __restrict__ Bt, int N, int K,
    _Float16* __restrict__ out0, const float* __restrict__ bias0,
    float* __restrict__ outf) {
  const int tid = threadIdx.x;
  const int w = tid >> 6, lane = tid & 63, g = lane >> 4, m = lane & 15;
  const int row0 = blockIdx.y * 64 + w * 16;
  const int c0 = blockIdx.x * 64;
  f32x4 acc[4] = {};
  const _Float16* Ap = A + (size_t)(row0 + m) * K + g * 8;
  const _Float16* Bp = Bt + (size_t)(c0 + m) * K + g * 8;
  for (int k0 = 0; k0 < K; k0 += 32) {
    f16x8 a = *(const f16x8*)(Ap + k0);
#pragma unroll
    for (int cf = 0; cf < 4; ++cf) {
      f16x8 bfr = *(const f16x8*)(Bp + (size_t)cf * 16 * K + k0);
      acc[cf] = MFMA16(a, bfr, acc[cf]);
    }
  }
#pragma unroll
  for (int cf = 0; cf < 4; ++cf) {
    const int col = c0 + cf * 16 + m;
    const int hh = col >> 6, dk = col & 63;
#pragma unroll
    for (int r = 0; r < 4; ++r) {
      const int row = row0 + g * 4 + r;
      const float v = acc[cf][r];
      if (MODE == 3) {
        out0[((size_t)hh * 4096 + row) * 64 + dk] = (_Float16)v;
      } else {
        outf[(size_t)row * N + col] = v + bias0[col];
      }
    }
  }
}

// ---------------- fused rel-pos attention, 4-way split over j ----------------
// grid (128 i-tiles of 16 rows, 16 b*h, 4 j-chunks), 64 threads = 1 wave.
// Chunk z handles j-tiles [z*8, z*8+8); writes unnormalized partials (m, l, acc).
__global__ __launch_bounds__(64) void attn_kernel(
    const _Float16* __restrict__ qc, const _Float16* __restrict__ qp,
    const _Float16* __restrict__ kb, const _Float16* __restrict__ vtb,
    const _Float16* __restrict__ relkb,
    float* __restrict__ pm, float* __restrict__ pl, _Float16* __restrict__ pacc) {
  __shared__ __align__(16) _Float16 P_lds[16][72];  // rows 144B (16B-aligned)
  const int lane = threadIdx.x;
  const int g = lane >> 4, m = lane & 15;
  const int i0 = blockIdx.x * 16;
  const int bh = blockIdx.y;
  const int h = bh & 7;
  const int z = blockIdx.z;

  const size_t qbase = ((size_t)bh * 2048 + i0 + m) * 64 + g * 8;
  f16x8 qcf0 = *(const f16x8*)(qc + qbase);
  f16x8 qcf1 = *(const f16x8*)(qc + qbase + 32);
  f16x8 qpf0 = *(const f16x8*)(qp + qbase);
  f16x8 qpf1 = *(const f16x8*)(qp + qbase + 32);

  f32x4 acc_o[4] = {};
  float m_run[4], l_run[4];
#pragma unroll
  for (int r = 0; r < 4; ++r) { m_run[r] = -1e30f; l_run[r] = 0.f; }

  for (int jt = z * 8; jt < z * 8 + 8; ++jt) {
    const int j0 = jt * 64;
    // ---- content logits S_c [16 x 64] ----
    f32x4 sc[4] = {};
    const size_t kbase = ((size_t)bh * 2048 + j0 + m) * 64 + g * 8;
#pragma unroll
    for (int cf = 0; cf < 4; ++cf) {
      f16x8 b0 = *(const f16x8*)(kb + kbase + (size_t)cf * 1024);
      f16x8 b1 = *(const f16x8*)(kb + kbase + (size_t)cf * 1024 + 32);
      sc[cf] = MFMA16(qcf0, b0, sc[cf]);
      sc[cf] = MFMA16(qcf1, b1, sc[cf]);
    }
    // ---- rel logits band R [16 x 80], d0p = j0 - i0 + 2032 ----
    const int d0p = j0 - i0 + 2032;  // rows d0p+c' in [0, 4095]
    const size_t rbase = ((size_t)h * 4096 + d0p + m) * 64 + g * 8;
    f32x4 rc[5] = {};
#pragma unroll
    for (int cf = 0; cf < 5; ++cf) {
      f16x8 b0 = *(const f16x8*)(relkb + rbase + (size_t)cf * 1024);
      f16x8 b1 = *(const f16x8*)(relkb + rbase + (size_t)cf * 1024 + 32);
      rc[cf] = MFMA16(qpf0, b0, rc[cf]);
      rc[cf] = MFMA16(qpf1, b1, rc[cf]);
    }
    // ---- in-register shift gather + add ----
#pragma unroll
    for (int r = 0; r < 4; ++r) {
      const int lr = g * 4 + r;
      const int u = 15 + m - lr;          // in [0, 30]
      const int src = (g << 4) | (u & 15);
      const bool hi = (m > lr);           // u >= 16
      float sh0 = __shfl(rc[0][r], src);
      float sh1 = __shfl(rc[1][r], src);
      float sh2 = __shfl(rc[2][r], src);
      float sh3 = __shfl(rc[3][r], src);
      float sh4 = __shfl(rc[4][r], src);
      sc[0][r] += hi ? sh1 : sh0;
      sc[1][r] += hi ? sh2 : sh1;
      sc[2][r] += hi ? sh3 : sh2;
      sc[3][r] += hi ? sh4 : sh3;
    }
    // ---- online softmax (rows owned per lane: r=0..3) ----
    float P[4][4];
#pragma unroll
    for (int r = 0; r < 4; ++r) {
      float mx = fmaxf(fmaxf(sc[0][r], sc[1][r]), fmaxf(sc[2][r], sc[3][r]));
      mx = fmaxf(mx, __shfl_xor(mx, 1));
      mx = fmaxf(mx, __shfl_xor(mx, 2));
      mx = fmaxf(mx, __shfl_xor(mx, 4));
      mx = fmaxf(mx, __shfl_xor(mx, 8));
      const float mnew = fmaxf(m_run[r], mx);
      const float corr = __expf(m_run[r] - mnew);
      float rs = 0.f;
#pragma unroll
      for (int cf = 0; cf < 4; ++cf) {
        float p = __expf(sc[cf][r] - mnew);
        P[cf][r] = p;
        rs += p;
      }
      rs += __shfl_xor(rs, 1);
      rs += __shfl_xor(rs, 2);
      rs += __shfl_xor(rs, 4);
      rs += __shfl_xor(rs, 8);
      l_run[r] = l_run[r] * corr + rs;
      m_run[r] = mnew;
#pragma unroll
      for (int cf = 0; cf < 4; ++cf) acc_o[cf][r] *= corr;
    }
    // ---- P -> fp16 -> wave-private LDS (no barrier; same-wave DS ops are ordered) ----
#pragma unroll
    for (int cf = 0; cf < 4; ++cf)
#pragma unroll
      for (int r = 0; r < 4; ++r)
        P_lds[g * 4 + r][cf * 16 + m] = (_Float16)P[cf][r];
    // ---- PV: acc_o += P . V ----
    const size_t vbase = ((size_t)bh * 64 + m) * 2048 + j0 + g * 8;
#pragma unroll
    for (int ks = 0; ks < 2; ++ks) {
      f16x8 pa = *(const f16x8*)(&P_lds[m][ks * 32 + g * 8]);
#pragma unroll
      for (int cf = 0; cf < 4; ++cf) {
        f16x8 vf = *(const f16x8*)(vtb + vbase + (size_t)cf * 32768 + ks * 32);
        acc_o[cf] = MFMA16(pa, vf, acc_o[cf]);
      }
    }
  }
  // ---- epilogue: write partials (unnormalized) ----
  const size_t prow = ((size_t)z * 16 + bh) * 2048 + i0;  // + local row
  if (m == 0) {
#pragma unroll
    for (int r = 0; r < 4; ++r) {
      pm[prow + g * 4 + r] = m_run[r];
      pl[prow + g * 4 + r] = l_run[r];
    }
  }
#pragma unroll
  for (int cf = 0; cf < 4; ++cf)
#pragma unroll
    for (int r = 0; r < 4; ++r)
      pacc[(prow + g * 4 + r) * 64 + cf * 16 + m] = (_Float16)acc_o[cf][r];
}

// ---------------- combine 4 partials -> attnb [b][n][h*64+dv] fp16 ----------------
__global__ __launch_bounds__(256) void combine_kernel(
    const float* __restrict__ pm, const float* __restrict__ pl,
    const _Float16* __restrict__ pacc, _Float16* __restrict__ attnb) {
  const int idx = blockIdx.x * 256 + threadIdx.x;  // 16*2048*64 = 2M
  const int col = idx & 63;
  const int row = idx >> 6;  // bh*2048 + i
  const float m0 = pm[row], m1 = pm[32768 + row], m2 = pm[65536 + row], m3 = pm[98304 + row];
  const float ms = fmaxf(fmaxf(m0, m1), fmaxf(m2, m3));
  const float s0 = __expf(m0 - ms), s1 = __expf(m1 - ms);
  const float s2 = __expf(m2 - ms), s3 = __expf(m3 - ms);
  const float l = pl[row] * s0 + pl[32768 + row] * s1 + pl[65536 + row] * s2 + pl[98304 + row] * s3;
  const size_t a = (size_t)row * 64 + col;
  float o = (float)pacc[a] * s0 + (float)pacc[a + 2097152] * s1 +
            (float)pacc[a + 4194304] * s2 + (float)pacc[a + 6291456] * s3;
  o /= l;
  const int bh = row >> 11, i = row & 2047;
  const int b = bh >> 3, h = bh & 7;
  attnb[((size_t)(b * 2048 + i)) * 512 + h * 64 + col] = (_Float16)o;
}

extern "C" void kernel_launch(void* const* d_in, const int* in_sizes, int n_in,
                              void* d_out, int out_size, void* d_ws, size_t ws_size,
                              hipStream_t stream) {
  (void)in_sizes; (void)n_in; (void)out_size; (void)ws_size;
  const float* x    = (const float*)d_in[0];
  const float* Wq   = (const float*)d_in[1];
  const float* Wk   = (const float*)d_in[2];
  const float* Wv   = (const float*)d_in[3];
  const float* Wrel = (const float*)d_in[4];
  const float* bc   = (const float*)d_in[5];  // rel_content_bias [8*64]
  const float* bp   = (const float*)d_in[6];  // rel_pos_bias [8*64]
  const float* Wo   = (const float*)d_in[7];
  const float* bo   = (const float*)d_in[8];
  float* out = (float*)d_out;

  char* ws = (char*)d_ws;
  size_t off = 0;
  auto alloc = [&](size_t bytes) -> void* {
    void* p = ws + off;
    off += (bytes + 255) & ~(size_t)255;
    return p;
  };
  _Float16* xb     = (_Float16*)alloc(4096ull * 768 * 2);    // x in fp16
  _Float16* wqkvt  = (_Float16*)alloc(1536ull * 768 * 2);    // [Wq;Wk;Wv]^T fp16
  _Float16* wrelt  = (_Float16*)alloc(512ull * 192 * 2);
  _Float16* wot    = (_Float16*)alloc(768ull * 512 * 2);
  _Float16* posb   = (_Float16*)alloc(4096ull * 192 * 2);    // positional features (row 4095 = 0)
  float*    lnrm   = (float*)alloc(32 * 4);                  // gamma log-norm constants
  _Float16* qcb    = (_Float16*)alloc(16ull * 2048 * 64 * 2);   // (q*scale + bc)  [b][h][n][64]
  _Float16* qpb    = (_Float16*)alloc(16ull * 2048 * 64 * 2);   // (q*scale + bp)
  _Float16* kbb    = (_Float16*)alloc(16ull * 2048 * 64 * 2);   // k [b][h][n][64]
  _Float16* vtb    = (_Float16*)alloc(16ull * 64 * 2048 * 2);   // v^T [b][h][64][n]
  _Float16* relkb  = (_Float16*)alloc(8ull * 4096 * 64 * 2);    // rel_k [h][4096][64]
  _Float16* attnb  = (_Float16*)alloc(4096ull * 512 * 2);       // attention output fp16
  float*    pm     = (float*)alloc(4ull * 32768 * 4);           // partial max [4][16][2048]
  float*    pl     = (float*)alloc(4ull * 32768 * 4);           // partial sum
  _Float16* pacc   = (_Float16*)alloc(4ull * 32768 * 64 * 2);   // partial acc [4][16][2048][64]

  cvt4_kernel<<<3072, 256, 0, stream>>>(x, xb, 786432);
  cvt_t3_kernel<<<4608, 256, 0, stream>>>(Wq, Wk, Wv, wqkvt);
  cvt_t_kernel<<<384, 256, 0, stream>>>(Wrel, wrelt, 192, 512);
  cvt_t_kernel<<<1536, 256, 0, stream>>>(Wo, wot, 512, 768);
  pos_const_kernel<<<1, 64, 0, stream>>>(lnrm);
  pos_embed_kernel<<<4096, 128, 0, stream>>>(posb, lnrm);

  gemm_qkv<<<dim3(24, 64), 256, 0, stream>>>(xb, wqkvt, qcb, qpb, kbb, vtb, bc, bp);
  gemm_bt<3><<<dim3(8, 64), 256, 0, stream>>>(posb, wrelt, 512, 192, relkb, nullptr, nullptr);

  attn_kernel<<<dim3(128, 16, 4), 64, 0, stream>>>(qcb, qpb, kbb, vtb, relkb, pm, pl, pacc);
  combine_kernel<<<8192, 256, 0, stream>>>(pm, pl, pacc, attnb);

  gemm_bt<4><<<dim3(12, 64), 256, 0, stream>>>(attnb, wot, 768, 512, nullptr, bo, out);
}

// Round 5
// 307.432 us; speedup vs baseline: 1.4247x; 1.4247x over previous
//
#include <hip/hip_runtime.h>
#include <hip/hip_bf16.h>
#include <math.h>

// Sizes (fixed): BATCH=2, SEQ=2048, DIM=768, HEADS=8, DK=DV=64, F=192, d_inner=512
// All internal compute in fp16 storage + fp32 MFMA accumulation.

typedef _Float16 f16x8 __attribute__((ext_vector_type(8)));
typedef _Float16 f16x4 __attribute__((ext_vector_type(4)));
typedef float f32x4 __attribute__((ext_vector_type(4)));

#define MFMA16(a, b, c) __builtin_amdgcn_mfma_f32_16x16x32_f16((a), (b), (c), 0, 0, 0)

// ---------------- f32 -> fp16 elementwise (vectorized x4) ----------------
__global__ __launch_bounds__(256) void cvt4_kernel(const float* __restrict__ in,
                                                   _Float16* __restrict__ out, int n4) {
  int idx = blockIdx.x * 256 + threadIdx.x;
  if (idx < n4) {
    float4 v = ((const float4*)in)[idx];
    f16x4 o;
    o[0] = (_Float16)v.x; o[1] = (_Float16)v.y; o[2] = (_Float16)v.z; o[3] = (_Float16)v.w;
    ((f16x4*)out)[idx] = o;
  }
}

// ---------------- f32 [K][N] -> fp16 transposed [N][K] ----------------
__global__ __launch_bounds__(256) void cvt_t_kernel(const float* __restrict__ in,
                                                    _Float16* __restrict__ out, int K, int N) {
  int idx = blockIdx.x * 256 + threadIdx.x;
  if (idx < K * N) {
    int k = idx / N, c = idx % N;
    out[(size_t)c * K + k] = (_Float16)in[idx];
  }
}

// ---- three [768][512] f32 weights -> one fp16 transposed [1536][768] ----
__global__ __launch_bounds__(256) void cvt_t3_kernel(const float* __restrict__ Wq,
                                                     const float* __restrict__ Wk,
                                                     const float* __restrict__ Wv,
                                                     _Float16* __restrict__ out) {
  int idx = blockIdx.x * 256 + threadIdx.x;  // over 3*768*512
  const int per = 768 * 512;
  int sel = idx / per, rem = idx - sel * per;
  int k = rem / 512, c = rem % 512;
  const float* W = (sel == 0) ? Wq : (sel == 1) ? Wk : Wv;
  out[((size_t)sel * 512 + c) * 768 + k] = (_Float16)W[rem];
}

// ---- gamma-basis row-invariant constants: lnrm[i] = lgamma(conc) - conc*log(rate) ----
__global__ __launch_bounds__(64) void pos_const_kernel(float* __restrict__ lnrm) {
  int t = threadIdx.x;
  if (t < 32) {
    float mean = 64.f * (float)(t + 1);
    float sd = 32.f;
    float conc = (mean / sd) * (mean / sd);
    float rate = mean / (sd * sd);
    lnrm[t] = lgammaf(conc) - conc * logf(rate);
  }
}

// ---------------- positional embedding: posb [4096][192] fp16 ----------------
__global__ __launch_bounds__(128) void pos_embed_kernel(_Float16* __restrict__ posb,
                                                        const float* __restrict__ lnrm) {
  __shared__ float sg[32];
  const int r = blockIdx.x, t = threadIdx.x;
  if (r >= 4095) {
    if (t < 96) {
      posb[(size_t)r * 192 + t] = (_Float16)0.f;
      posb[(size_t)r * 192 + 96 + t] = (_Float16)0.f;
    }
    return;
  }
  const float dist = (float)(r - 2047);
  const float absd = fabsf(dist);
  const float sgn = (dist > 0.f) ? 1.f : ((dist < 0.f) ? -1.f : 0.f);
  float val = 0.f;
  if (t < 32) {
    float e = 3.f + (float)t * (8.f / 31.f);
    float hl = exp2f(e);
    val = exp2f(-absd / hl);
  } else if (t < 64) {
    int i = t - 32;
    float cw = exp2f((float)(i + 1)) - 1.f;
    val = (cw > absd) ? 1.f : 0.f;
  } else if (t < 96) {
    int i = t - 64;
    float mean = 64.f * (float)(i + 1);
    float sd = 32.f;
    float conc = (mean / sd) * (mean / sd);
    float rate = mean / (sd * sd);
    float lu = (conc - 1.f) * logf(absd) - rate * absd;
    val = expf(lu - lnrm[i]) + 1e-8f;
    sg[i] = val;
  }
  __syncthreads();
  if (t >= 64 && t < 96) {
    float mx = sg[0];
#pragma unroll
    for (int i = 1; i < 32; ++i) mx = fmaxf(mx, sg[i]);
    val = val / mx;
  }
  if (t < 96) {
    posb[(size_t)r * 192 + t] = (_Float16)val;
    posb[(size_t)r * 192 + 96 + t] = (_Float16)(sgn * val);
  }
}

// ---------------- fused QKV projection: [4096][768] x [1536][768]^T ----------------
__global__ __launch_bounds__(256) void gemm_qkv(
    const _Float16* __restrict__ A, const _Float16* __restrict__ Bt,
    _Float16* __restrict__ qc, _Float16* __restrict__ qp,
    _Float16* __restrict__ kb, _Float16* __restrict__ vt,
    const float* __restrict__ bc, const float* __restrict__ bp) {
  const int tid = threadIdx.x;
  const int w = tid >> 6, lane = tid & 63, g = lane >> 4, m = lane & 15;
  const int row0 = blockIdx.y * 64 + w * 16;
  const int c0 = blockIdx.x * 64;
  f32x4 acc[4] = {};
  const _Float16* Ap = A + (size_t)(row0 + m) * 768 + g * 8;
  const _Float16* Bp = Bt + (size_t)(c0 + m) * 768 + g * 8;
  for (int k0 = 0; k0 < 768; k0 += 32) {
    f16x8 a = *(const f16x8*)(Ap + k0);
#pragma unroll
    for (int cf = 0; cf < 4; ++cf) {
      f16x8 bfr = *(const f16x8*)(Bp + (size_t)cf * 16 * 768 + k0);
      acc[cf] = MFMA16(a, bfr, acc[cf]);
    }
  }
  const int proj = c0 >> 9;  // uniform per block
#pragma unroll
  for (int cf = 0; cf < 4; ++cf) {
    const int col = c0 + cf * 16 + m;
    const int c = col & 511, hh = c >> 6, dk = c & 63;
    float b0 = 0.f, b1 = 0.f;
    if (proj == 0) { b0 = bc[c]; b1 = bp[c]; }
#pragma unroll
    for (int r = 0; r < 4; ++r) {
      const int row = row0 + g * 4 + r;
      const int bb = row >> 11, n = row & 2047;
      const float v = acc[cf][r];
      if (proj == 0) {
        const size_t ad = ((size_t)(bb * 8 + hh) * 2048 + n) * 64 + dk;
        const float vs = v * 0.125f;  // DIM_KEY^-0.5
        qc[ad] = (_Float16)(vs + b0);
        qp[ad] = (_Float16)(vs + b1);
      } else if (proj == 1) {
        kb[((size_t)(bb * 8 + hh) * 2048 + n) * 64 + dk] = (_Float16)v;
      } else {
        vt[((size_t)(bb * 8 + hh) * 64 + dk) * 2048 + n] = (_Float16)v;
      }
    }
  }
}

// ---------------- generic MFMA GEMM: C[M][*] = A[M][K] * Bt[N][K]^T ----------------
// MODE 3: relk -> fp16 [h][4096][64]; MODE 4: out-proj -> f32 [row][N] + bias0[col]
template <int MODE>
__global__ __launch_bounds__(256) void gemm_bt(
    const _Float16* __restrict__ A, const _Float16* __restrict__ Bt, int N, int K,
    _Float16* __restrict__ out0, const float* __restrict__ bias0,
    float* __restrict__ outf) {
  const int tid = threadIdx.x;
  const int w = tid >> 6, lane = tid & 63, g = lane >> 4, m = lane & 15;
  const int row0 = blockIdx.y * 64 + w * 16;
  const int c0 = blockIdx.x * 64;
  f32x4 acc[4] = {};
  const _Float16* Ap = A + (size_t)(row0 + m) * K + g * 8;
  const _Float16* Bp = Bt + (size_t)(c0 + m) * K + g * 8;
  for (int k0 = 0; k0 < K; k0 += 32) {
    f16x8 a = *(const f16x8*)(Ap + k0);
#pragma unroll
    for (int cf = 0; cf < 4; ++cf) {
      f16x8 bfr = *(const f16x8*)(Bp + (size_t)cf * 16 * K + k0);
      acc[cf] = MFMA16(a, bfr, acc[cf]);
    }
  }
#pragma unroll
  for (int cf = 0; cf < 4; ++cf) {
    const int col = c0 + cf * 16 + m;
    const int hh = col >> 6, dk = col & 63;
#pragma unroll
    for (int r = 0; r < 4; ++r) {
      const int row = row0 + g * 4 + r;
      const float v = acc[cf][r];
      if (MODE == 3) {
        out0[((size_t)hh * 4096 + row) * 64 + dk] = (_Float16)v;
      } else {
        outf[(size_t)row * N + col] = v + bias0[col];
      }
    }
  }
}

// ---------------- fused rel-pos attention: 4-wave block, shared LDS staging ----------------
// grid 512 blocks x 256 threads. Block L: h = L&7, b = (L>>3)>>5, xt = (L>>3)&31.
// Block rows [i0b, i0b+64), wave w owns [i0b+16w, +16). Per 64-wide j-tile:
// stage K[64][64], V^T[64][64], relk[128][64] (union band) into LDS (double-buffered,
// slot^(row&7) XOR swizzle); all waves read MFMA fragments from LDS. Barrier-per-tile.
__global__ __launch_bounds__(256, 2) void attn_kernel(
    const _Float16* __restrict__ qc, const _Float16* __restrict__ qp,
    const _Float16* __restrict__ kb, const _Float16* __restrict__ vtb,
    const _Float16* __restrict__ relkb, _Float16* __restrict__ attnb) {
  __shared__ __align__(16) char lds[2 * 32768 + 4 * 2304];  // 2x(K 8K | V 8K | R 16K) + P
  const int tid = threadIdx.x;
  const int w = tid >> 6, lane = tid & 63, g = lane >> 4, m = lane & 15;
  const int L = blockIdx.x;
  const int h = L & 7;
  const int r2 = L >> 3;
  const int b = r2 >> 5, xt = r2 & 31;
  const int bh = b * 8 + h;
  const int i0b = xt << 6;
  const int i0 = i0b + w * 16;

  // ---- staging geometry: thread covers 16B slots; row = slot>>3, sl = slot&7 ----
  const int srow = tid >> 3;  // 0..31
  const int ssl = tid & 7;
  const int swz = (srow << 7) + ((ssl ^ (srow & 7)) << 4);  // swizzled LDS byte offset
  const char* kgb = (const char*)kb + ((size_t)bh << 18);    // + (j0+row)*128 + sl*16
  const char* vgb = (const char*)vtb + ((size_t)bh << 18);   // + row*4096 + j0*2 + sl*16
  const char* rgb = (const char*)relkb + ((size_t)h << 19);  // + (d0+row)*128 + sl*16

  f16x8 ska, skb_, sva, svb, sra, srb, src_, srd;
#define STAGE_LOAD(j0v, d0v)                                                          \
  ska  = *(const f16x8*)(kgb + ((size_t)((j0v) + srow) << 7) + (ssl << 4));           \
  skb_ = *(const f16x8*)(kgb + ((size_t)((j0v) + srow + 32) << 7) + (ssl << 4));      \
  sva  = *(const f16x8*)(vgb + ((size_t)srow << 12) + ((j0v) << 1) + (ssl << 4));     \
  svb  = *(const f16x8*)(vgb + ((size_t)(srow + 32) << 12) + ((j0v) << 1) + (ssl << 4)); \
  sra  = *(const f16x8*)(rgb + ((size_t)((d0v) + srow) << 7) + (ssl << 4));           \
  srb  = *(const f16x8*)(rgb + ((size_t)((d0v) + srow + 32) << 7) + (ssl << 4));      \
  src_ = *(const f16x8*)(rgb + ((size_t)((d0v) + srow + 64) << 7) + (ssl << 4));      \
  srd  = *(const f16x8*)(rgb + ((size_t)((d0v) + srow + 96) << 7) + (ssl << 4));

#define STAGE_WRITE(halfp)                          \
  *(f16x8*)((halfp) + swz) = ska;                   \
  *(f16x8*)((halfp) + swz + 4096) = skb_;           \
  *(f16x8*)((halfp) + 8192 + swz) = sva;            \
  *(f16x8*)((halfp) + 8192 + swz + 4096) = svb;     \
  *(f16x8*)((halfp) + 16384 + swz) = sra;           \
  *(f16x8*)((halfp) + 16384 + swz + 4096) = srb;    \
  *(f16x8*)((halfp) + 16384 + swz + 8192) = src_;   \
  *(f16x8*)((halfp) + 16384 + swz + 12288) = srd;

  // ---- prologue: stage tile 0 into buffer 0 ----
  STAGE_LOAD(0, 1984 - i0b);
  { char* nh = lds; STAGE_WRITE(nh); }

  const size_t qbase = ((size_t)bh * 2048 + i0 + m) * 64 + g * 8;
  f16x8 qcf0 = *(const f16x8*)(qc + qbase);
  f16x8 qcf1 = *(const f16x8*)(qc + qbase + 32);
  f16x8 qpf0 = *(const f16x8*)(qp + qbase);
  f16x8 qpf1 = *(const f16x8*)(qp + qbase + 32);

  __syncthreads();

  f32x4 acc_o[4] = {};
  float m_run[4], l_run[4];
#pragma unroll
  for (int r = 0; r < 4; ++r) { m_run[r] = -1e30f; l_run[r] = 0.f; }

  // fragment-read swizzled slot offsets (ks=0/1)
  const int sx = m & 7;
  const int fo0 = (g ^ sx) << 4;
  const int fo1 = ((4 | g) ^ sx) << 4;
  const int rrow0 = 48 - (w << 4) + m;  // rel band local row for cf=0
  _Float16* Pl = (_Float16*)(lds + 65536 + w * 2304);  // per-wave [16][72]

  for (int jt = 0; jt < 32; ++jt) {
    if (jt < 31) {
      const int j0n = (jt + 1) << 6;
      STAGE_LOAD(j0n, j0n - i0b + 1984);
    }
    const char* curh = lds + ((jt & 1) << 15);
    // ---- content logits S_c [16 x 64] ----
    f32x4 sc[4] = {};
#pragma unroll
    for (int cf = 0; cf < 4; ++cf) {
      const char* kp = curh + ((m + (cf << 4)) << 7);
      sc[cf] = MFMA16(qcf0, *(const f16x8*)(kp + fo0), sc[cf]);
      sc[cf] = MFMA16(qcf1, *(const f16x8*)(kp + fo1), sc[cf]);
    }
    // ---- rel logits band R [16 x 80] ----
    f32x4 rc[5] = {};
#pragma unroll
    for (int cf = 0; cf < 5; ++cf) {
      const char* rp = curh + 16384 + ((rrow0 + (cf << 4)) << 7);
      rc[cf] = MFMA16(qpf0, *(const f16x8*)(rp + fo0), rc[cf]);
      rc[cf] = MFMA16(qpf1, *(const f16x8*)(rp + fo1), rc[cf]);
    }
    // ---- in-register shift gather + add ----
#pragma unroll
    for (int r = 0; r < 4; ++r) {
      const int lr = g * 4 + r;
      const int u = 15 + m - lr;          // in [0, 30]
      const int src = (g << 4) | (u & 15);
      const bool hi = (m > lr);           // u >= 16
      float sh0 = __shfl(rc[0][r], src);
      float sh1 = __shfl(rc[1][r], src);
      float sh2 = __shfl(rc[2][r], src);
      float sh3 = __shfl(rc[3][r], src);
      float sh4 = __shfl(rc[4][r], src);
      sc[0][r] += hi ? sh1 : sh0;
      sc[1][r] += hi ? sh2 : sh1;
      sc[2][r] += hi ? sh3 : sh2;
      sc[3][r] += hi ? sh4 : sh3;
    }
    // ---- online softmax ----
    float P[4][4];
#pragma unroll
    for (int r = 0; r < 4; ++r) {
      float mx = fmaxf(fmaxf(sc[0][r], sc[1][r]), fmaxf(sc[2][r], sc[3][r]));
      mx = fmaxf(mx, __shfl_xor(mx, 1));
      mx = fmaxf(mx, __shfl_xor(mx, 2));
      mx = fmaxf(mx, __shfl_xor(mx, 4));
      mx = fmaxf(mx, __shfl_xor(mx, 8));
      const float mnew = fmaxf(m_run[r], mx);
      const float corr = __expf(m_run[r] - mnew);
      float rs = 0.f;
#pragma unroll
      for (int cf = 0; cf < 4; ++cf) {
        float p = __expf(sc[cf][r] - mnew);
        P[cf][r] = p;
        rs += p;
      }
      rs += __shfl_xor(rs, 1);
      rs += __shfl_xor(rs, 2);
      rs += __shfl_xor(rs, 4);
      rs += __shfl_xor(rs, 8);
      l_run[r] = l_run[r] * corr + rs;
      m_run[r] = mnew;
#pragma unroll
      for (int cf = 0; cf < 4; ++cf) acc_o[cf][r] *= corr;
    }
    // ---- P -> fp16 -> wave-private LDS (same-wave DS ordering, no barrier) ----
#pragma unroll
    for (int cf = 0; cf < 4; ++cf)
#pragma unroll
      for (int r = 0; r < 4; ++r)
        Pl[(g * 4 + r) * 72 + cf * 16 + m] = (_Float16)P[cf][r];
    // ---- PV: acc_o += P . V (V from LDS) ----
#pragma unroll
    for (int ks = 0; ks < 2; ++ks) {
      f16x8 pa = *(const f16x8*)((const char*)Pl + m * 144 + ks * 64 + (g << 4));
#pragma unroll
      for (int cf = 0; cf < 4; ++cf) {
        const char* vp = curh + 8192 + ((m + (cf << 4)) << 7);
        acc_o[cf] = MFMA16(pa, *(const f16x8*)(vp + (ks ? fo1 : fo0)), acc_o[cf]);
      }
    }
    // ---- write staged t+1 into the other buffer, then sync ----
    if (jt < 31) {
      char* nh = lds + (((jt & 1) ^ 1) << 15);
      STAGE_WRITE(nh);
    }
    __syncthreads();
  }
  // ---- epilogue: normalize, write attn output [b][n][h*64+dv] fp16 ----
#pragma unroll
  for (int cf = 0; cf < 4; ++cf)
#pragma unroll
    for (int r = 0; r < 4; ++r) {
      const int i = i0 + g * 4 + r;
      const float o = acc_o[cf][r] / l_run[r];
      attnb[((size_t)(b * 2048 + i)) * 512 + h * 64 + cf * 16 + m] = (_Float16)o;
    }
#undef STAGE_LOAD
#undef STAGE_WRITE
}

extern "C" void kernel_launch(void* const* d_in, const int* in_sizes, int n_in,
                              void* d_out, int out_size, void* d_ws, size_t ws_size,
                              hipStream_t stream) {
  (void)in_sizes; (void)n_in; (void)out_size; (void)ws_size;
  const float* x    = (const float*)d_in[0];
  const float* Wq   = (const float*)d_in[1];
  const float* Wk   = (const float*)d_in[2];
  const float* Wv   = (const float*)d_in[3];
  const float* Wrel = (const float*)d_in[4];
  const float* bc   = (const float*)d_in[5];  // rel_content_bias [8*64]
  const float* bp   = (const float*)d_in[6];  // rel_pos_bias [8*64]
  const float* Wo   = (const float*)d_in[7];
  const float* bo   = (const float*)d_in[8];
  float* out = (float*)d_out;

  char* ws = (char*)d_ws;
  size_t off = 0;
  auto alloc = [&](size_t bytes) -> void* {
    void* p = ws + off;
    off += (bytes + 255) & ~(size_t)255;
    return p;
  };
  _Float16* xb     = (_Float16*)alloc(4096ull * 768 * 2);    // x in fp16
  _Float16* wqkvt  = (_Float16*)alloc(1536ull * 768 * 2);    // [Wq;Wk;Wv]^T fp16
  _Float16* wrelt  = (_Float16*)alloc(512ull * 192 * 2);
  _Float16* wot    = (_Float16*)alloc(768ull * 512 * 2);
  _Float16* posb   = (_Float16*)alloc(4096ull * 192 * 2);    // positional features (row 4095 = 0)
  float*    lnrm   = (float*)alloc(32 * 4);                  // gamma log-norm constants
  _Float16* qcb    = (_Float16*)alloc(16ull * 2048 * 64 * 2);   // (q*scale + bc)  [b][h][n][64]
  _Float16* qpb    = (_Float16*)alloc(16ull * 2048 * 64 * 2);   // (q*scale + bp)
  _Float16* kbb    = (_Float16*)alloc(16ull * 2048 * 64 * 2);   // k [b][h][n][64]
  _Float16* vtb    = (_Float16*)alloc(16ull * 64 * 2048 * 2);   // v^T [b][h][64][n]
  _Float16* relkb  = (_Float16*)alloc(8ull * 4096 * 64 * 2);    // rel_k [h][4096][64]
  _Float16* attnb  = (_Float16*)alloc(4096ull * 512 * 2);       // attention output fp16

  cvt4_kernel<<<3072, 256, 0, stream>>>(x, xb, 786432);
  cvt_t3_kernel<<<4608, 256, 0, stream>>>(Wq, Wk, Wv, wqkvt);
  cvt_t_kernel<<<384, 256, 0, stream>>>(Wrel, wrelt, 192, 512);
  cvt_t_kernel<<<1536, 256, 0, stream>>>(Wo, wot, 512, 768);
  pos_const_kernel<<<1, 64, 0, stream>>>(lnrm);
  pos_embed_kernel<<<4096, 128, 0, stream>>>(posb, lnrm);

  gemm_qkv<<<dim3(24, 64), 256, 0, stream>>>(xb, wqkvt, qcb, qpb, kbb, vtb, bc, bp);
  gemm_bt<3><<<dim3(8, 64), 256, 0, stream>>>(posb, wrelt, 512, 192, relkb, nullptr, nullptr);

  attn_kernel<<<512, 256, 0, stream>>>(qcb, qpb, kbb, vtb, relkb, attnb);

  gemm_bt<4><<<dim3(12, 64), 256, 0, stream>>>(attnb, wot, 768, 512, nullptr, bo, out);
}

// Round 7
// 213.493 us; speedup vs baseline: 2.0516x; 1.4400x over previous
//
#include <hip/hip_runtime.h>
#include <hip/hip_bf16.h>
#include <math.h>

// Sizes (fixed): BATCH=2, SEQ=2048, DIM=768, HEADS=8, DK=DV=64, F=192, d_inner=512
// All internal compute in fp16 storage + fp32 MFMA accumulation.

typedef _Float16 f16x8 __attribute__((ext_vector_type(8)));
typedef _Float16 f16x4 __attribute__((ext_vector_type(4)));
typedef float f32x4 __attribute__((ext_vector_type(4)));

#define MFMA16(a, b, c) __builtin_amdgcn_mfma_f32_16x16x32_f16((a), (b), (c), 0, 0, 0)

// ---------------- f32 -> fp16 elementwise (vectorized x4) ----------------
__global__ __launch_bounds__(256) void cvt4_kernel(const float* __restrict__ in,
                                                   _Float16* __restrict__ out, int n4) {
  int idx = blockIdx.x * 256 + threadIdx.x;
  if (idx < n4) {
    float4 v = ((const float4*)in)[idx];
    f16x4 o;
    o[0] = (_Float16)v.x; o[1] = (_Float16)v.y; o[2] = (_Float16)v.z; o[3] = (_Float16)v.w;
    ((f16x4*)out)[idx] = o;
  }
}

// ---------------- tiled transpose f32 [K][N] -> fp16 [N][K] ----------------
// 32x32 tile per block, 256 threads: coalesced float4 loads, packed f16x4 stores.
__global__ __launch_bounds__(256) void cvt_t_tile_kernel(const float* __restrict__ in,
                                                         _Float16* __restrict__ out,
                                                         int K, int N) {
  __shared__ float tile[32][33];
  const int k0 = blockIdx.y * 32, n0 = blockIdx.x * 32;
  const int t = threadIdx.x;
  const int tr = t >> 3, tc = (t & 7) * 4;
  float4 v = *(const float4*)(in + (size_t)(k0 + tr) * N + n0 + tc);
  tile[tr][tc] = v.x; tile[tr][tc + 1] = v.y; tile[tr][tc + 2] = v.z; tile[tr][tc + 3] = v.w;
  __syncthreads();
  f16x4 o;
  o[0] = (_Float16)tile[tc][tr];
  o[1] = (_Float16)tile[tc + 1][tr];
  o[2] = (_Float16)tile[tc + 2][tr];
  o[3] = (_Float16)tile[tc + 3][tr];
  *(f16x4*)(out + (size_t)(n0 + tr) * K + k0 + tc) = o;
}

// ---- three [768][512] f32 weights -> one fp16 transposed [1536][768], tiled ----
__global__ __launch_bounds__(256) void cvt_t3_tile_kernel(const float* __restrict__ Wq,
                                                          const float* __restrict__ Wk,
                                                          const float* __restrict__ Wv,
                                                          _Float16* __restrict__ out) {
  __shared__ float tile[32][33];
  const int z = blockIdx.z;
  const float* in = (z == 0) ? Wq : (z == 1) ? Wk : Wv;
  const int k0 = blockIdx.y * 32, n0 = blockIdx.x * 32;
  const int t = threadIdx.x;
  const int tr = t >> 3, tc = (t & 7) * 4;
  float4 v = *(const float4*)(in + (size_t)(k0 + tr) * 512 + n0 + tc);
  tile[tr][tc] = v.x; tile[tr][tc + 1] = v.y; tile[tr][tc + 2] = v.z; tile[tr][tc + 3] = v.w;
  __syncthreads();
  f16x4 o;
  o[0] = (_Float16)tile[tc][tr];
  o[1] = (_Float16)tile[tc + 1][tr];
  o[2] = (_Float16)tile[tc + 2][tr];
  o[3] = (_Float16)tile[tc + 3][tr];
  *(f16x4*)(out + ((size_t)z * 512 + n0 + tr) * 768 + k0 + tc) = o;
}

// ---- gamma-basis row-invariant constants: lnrm[i] = lgamma(conc) - conc*log(rate) ----
__global__ __launch_bounds__(64) void pos_const_kernel(float* __restrict__ lnrm) {
  int t = threadIdx.x;
  if (t < 32) {
    float mean = 64.f * (float)(t + 1);
    float sd = 32.f;
    float conc = (mean / sd) * (mean / sd);
    float rate = mean / (sd * sd);
    lnrm[t] = lgammaf(conc) - conc * logf(rate);
  }
}

// ---------------- positional embedding: posb [4096][192] fp16 ----------------
// 4 rows per 128-thread block; thread (lr, i) computes exp/cmask/gamma for feature i.
// gamma row-max via shfl within the aligned 32-group. Row 4095 zeroed (pad).
__global__ __launch_bounds__(128) void pos_embed_kernel(_Float16* __restrict__ posb,
                                                        const float* __restrict__ lnrm) {
  const int t = threadIdx.x;
  const int lr = t >> 5, i = t & 31;
  const int r = blockIdx.x * 4 + lr;
  _Float16* row = posb + (size_t)r * 192;
  if (r >= 4095) {
    row[i] = (_Float16)0.f; row[32 + i] = (_Float16)0.f; row[64 + i] = (_Float16)0.f;
    row[96 + i] = (_Float16)0.f; row[128 + i] = (_Float16)0.f; row[160 + i] = (_Float16)0.f;
    return;
  }
  const float dist = (float)(r - 2047);
  const float absd = fabsf(dist);
  const float sgn = (dist > 0.f) ? 1.f : ((dist < 0.f) ? -1.f : 0.f);
  // exp basis: 2^(-absd / 2^e), e = linspace(3, 11, 32)
  const float e = 3.f + (float)i * (8.f / 31.f);
  const float expv = exp2f(-absd * exp2f(-e));
  // central mask
  const float cw = exp2f((float)(i + 1)) - 1.f;
  const float cm = (cw > absd) ? 1.f : 0.f;
  // gamma pdf, row-max normalized
  const float mean = 64.f * (float)(i + 1);
  const float conc = (mean / 32.f) * (mean / 32.f);
  const float rate = mean / 1024.f;
  const float lu = (conc - 1.f) * logf(absd) - rate * absd;
  float gv = expf(lu - lnrm[i]) + 1e-8f;
  float mx = gv;
  mx = fmaxf(mx, __shfl_xor(mx, 1));
  mx = fmaxf(mx, __shfl_xor(mx, 2));
  mx = fmaxf(mx, __shfl_xor(mx, 4));
  mx = fmaxf(mx, __shfl_xor(mx, 8));
  mx = fmaxf(mx, __shfl_xor(mx, 16));
  gv /= mx;
  row[i] = (_Float16)expv;       row[32 + i] = (_Float16)cm;        row[64 + i] = (_Float16)gv;
  row[96 + i] = (_Float16)(sgn * expv); row[128 + i] = (_Float16)(sgn * cm); row[160 + i] = (_Float16)(sgn * gv);
}

// ---------------- unified LDS-staged MFMA GEMM: C[M][*] = A[M][K] * Bt[N][K]^T ----------------
// 128x128 tile, BK=32, 256 thr = 4 waves (2x2 of 64x64), double-buffered swizzled LDS.
// MODE 0: qkv fused (N=1536): cols 0..511 -> qc/qp (scaled+bias), 512..1023 -> k, 1024..1535 -> vT
// MODE 3: relk -> fp16 [h][4096][64]
// MODE 4: out-proj -> f32 [row][N] + bias0[col]
template <int MODE>
__global__ __launch_bounds__(256, 3) void gemm_tile(
    const _Float16* __restrict__ A, const _Float16* __restrict__ Bt,
    const int N, const int K,
    _Float16* __restrict__ o0, _Float16* __restrict__ o1,
    _Float16* __restrict__ o2, _Float16* __restrict__ o3,
    const float* __restrict__ bias0, const float* __restrict__ bias1,
    float* __restrict__ outf) {
  __shared__ __align__(16) _Float16 As[2][128 * 32];
  __shared__ __align__(16) _Float16 Bs[2][128 * 32];
  const int tid = threadIdx.x;
  const int w = tid >> 6, lane = tid & 63, g = lane >> 4, m = lane & 15;
  const int wr = w >> 1, wc = w & 1;
  const int row0 = blockIdx.y * 128;
  const int c0 = blockIdx.x * 128;

  // staging: thread covers logical (row = tid>>2 [+64], slot = tid&3); swizzle slot^((row>>1)&3)
  const int sr0 = tid >> 2, ssl = tid & 3;
  const _Float16* Ag = A + (size_t)(row0 + sr0) * K + ssl * 8;
  const _Float16* Bg = Bt + (size_t)(c0 + sr0) * K + ssl * 8;
  const size_t gstep = (size_t)64 * K;
  const int wo0 = sr0 * 64 + ((ssl ^ ((sr0 >> 1) & 3)) << 4);  // byte offset; +4096 for row+64

  // fragment-read byte offsets (logical slot g -> phys g^((row>>1)&3))
  int aoff[4], boff[4];
#pragma unroll
  for (int i = 0; i < 4; ++i) {
    const int ar = wr * 64 + i * 16 + m;
    aoff[i] = ar * 64 + ((g ^ ((ar >> 1) & 3)) << 4);
    const int br = wc * 64 + i * 16 + m;
    boff[i] = br * 64 + ((g ^ ((br >> 1) & 3)) << 4);
  }

  f16x8 a0, a1, b0, b1;
#define GLOAD(k0v)                                      \
  a0 = *(const f16x8*)(Ag + (k0v));                     \
  a1 = *(const f16x8*)(Ag + gstep + (k0v));             \
  b0 = *(const f16x8*)(Bg + (k0v));                     \
  b1 = *(const f16x8*)(Bg + gstep + (k0v));
#define SWRITE(buf)                                     \
  *(f16x8*)((char*)As[buf] + wo0) = a0;                 \
  *(f16x8*)((char*)As[buf] + wo0 + 4096) = a1;          \
  *(f16x8*)((char*)Bs[buf] + wo0) = b0;                 \
  *(f16x8*)((char*)Bs[buf] + wo0 + 4096) = b1;

  f32x4 acc[4][4] = {};
  GLOAD(0); SWRITE(0);
  __syncthreads();
  const int nk = K >> 5;
  for (int ks = 0; ks < nk; ++ks) {
    const int cur = ks & 1;
    if (ks + 1 < nk) { GLOAD((ks + 1) << 5); }
    const char* ap = (const char*)As[cur];
    const char* bp = (const char*)Bs[cur];
    f16x8 af[4], bf[4];
#pragma unroll
    for (int i = 0; i < 4; ++i) {
      af[i] = *(const f16x8*)(ap + aoff[i]);
      bf[i] = *(const f16x8*)(bp + boff[i]);
    }
#pragma unroll
    for (int mi = 0; mi < 4; ++mi)
#pragma unroll
      for (int ni = 0; ni < 4; ++ni)
        acc[mi][ni] = MFMA16(af[mi], bf[ni], acc[mi][ni]);
    if (ks + 1 < nk) { SWRITE(cur ^ 1); }
    __syncthreads();
  }
#undef GLOAD
#undef SWRITE

  // ---- epilogue ----
  const int proj = (MODE == 0) ? (c0 >> 9) : 0;
#pragma unroll
  for (int ni = 0; ni < 4; ++ni) {
    const int col = c0 + wc * 64 + ni * 16 + m;
    const int c = col & 511, hh = (MODE == 0) ? (c >> 6) : (col >> 6);
    const int dk = col & 63;
    float b0f = 0.f, b1f = 0.f;
    if (MODE == 0 && proj == 0) { b0f = bias0[c]; b1f = bias1[c]; }
    if (MODE == 0 && proj == 2) {
      // vT: pack 4 consecutive n into one 8B store
#pragma unroll
      for (int mi = 0; mi < 4; ++mi) {
        const int rowb = row0 + wr * 64 + mi * 16 + g * 4;
        const int bb = rowb >> 11, n = rowb & 2047;
        f16x4 pk;
#pragma unroll
        for (int r = 0; r < 4; ++r) pk[r] = (_Float16)acc[mi][ni][r];
        *(f16x4*)(o3 + ((size_t)(bb * 8 + hh) * 64 + dk) * 2048 + n) = pk;
      }
    } else {
#pragma unroll
      for (int mi = 0; mi < 4; ++mi) {
#pragma unroll
        for (int r = 0; r < 4; ++r) {
          const int row = row0 + wr * 64 + mi * 16 + g * 4 + r;
          const float v = acc[mi][ni][r];
          if (MODE == 0) {
            const int bb = row >> 11, n = row & 2047;
            const size_t ad = ((size_t)(bb * 8 + hh) * 2048 + n) * 64 + dk;
            if (proj == 0) {
              const float vs = v * 0.125f;  // DIM_KEY^-0.5
              o0[ad] = (_Float16)(vs + b0f);
              o1[ad] = (_Float16)(vs + b1f);
            } else {  // proj == 1: k
              o2[ad] = (_Float16)v;
            }
          } else if (MODE == 3) {
            o0[((size_t)hh * 4096 + row) * 64 + dk] = (_Float16)v;
          } else {
            outf[(size_t)row * N + col] = v + bias0[col];
          }
        }
      }
    }
  }
}

// ---------------- fused rel-pos attention: 4-wave block, shared LDS staging ----------------
// (unchanged from R5 — passed at 95 us, FETCH 10 MB)
__global__ __launch_bounds__(256, 2) void attn_kernel(
    const _Float16* __restrict__ qc, const _Float16* __restrict__ qp,
    const _Float16* __restrict__ kb, const _Float16* __restrict__ vtb,
    const _Float16* __restrict__ relkb, _Float16* __restrict__ attnb) {
  __shared__ __align__(16) char lds[2 * 32768 + 4 * 2304];  // 2x(K 8K | V 8K | R 16K) + P
  const int tid = threadIdx.x;
  const int w = tid >> 6, lane = tid & 63, g = lane >> 4, m = lane & 15;
  const int L = blockIdx.x;
  const int h = L & 7;
  const int r2 = L >> 3;
  const int b = r2 >> 5, xt = r2 & 31;
  const int bh = b * 8 + h;
  const int i0b = xt << 6;
  const int i0 = i0b + w * 16;

  const int srow = tid >> 3;  // 0..31
  const int ssl = tid & 7;
  const int swz = (srow << 7) + ((ssl ^ (srow & 7)) << 4);
  const char* kgb = (const char*)kb + ((size_t)bh << 18);
  const char* vgb = (const char*)vtb + ((size_t)bh << 18);
  const char* rgb = (const char*)relkb + ((size_t)h << 19);

  f16x8 ska, skb_, sva, svb, sra, srb, src_, srd;
#define STAGE_LOAD(j0v, d0v)                                                          \
  ska  = *(const f16x8*)(kgb + ((size_t)((j0v) + srow) << 7) + (ssl << 4));           \
  skb_ = *(const f16x8*)(kgb + ((size_t)((j0v) + srow + 32) << 7) + (ssl << 4));      \
  sva  = *(const f16x8*)(vgb + ((size_t)srow << 12) + ((j0v) << 1) + (ssl << 4));     \
  svb  = *(const f16x8*)(vgb + ((size_t)(srow + 32) << 12) + ((j0v) << 1) + (ssl << 4)); \
  sra  = *(const f16x8*)(rgb + ((size_t)((d0v) + srow) << 7) + (ssl << 4));           \
  srb  = *(const f16x8*)(rgb + ((size_t)((d0v) + srow + 32) << 7) + (ssl << 4));      \
  src_ = *(const f16x8*)(rgb + ((size_t)((d0v) + srow + 64) << 7) + (ssl << 4));      \
  srd  = *(const f16x8*)(rgb + ((size_t)((d0v) + srow + 96) << 7) + (ssl << 4));

#define STAGE_WRITE(halfp)                          \
  *(f16x8*)((halfp) + swz) = ska;                   \
  *(f16x8*)((halfp) + swz + 4096) = skb_;           \
  *(f16x8*)((halfp) + 8192 + swz) = sva;            \
  *(f16x8*)((halfp) + 8192 + swz + 4096) = svb;     \
  *(f16x8*)((halfp) + 16384 + swz) = sra;           \
  *(f16x8*)((halfp) + 16384 + swz + 4096) = srb;    \
  *(f16x8*)((halfp) + 16384 + swz + 8192) = src_;   \
  *(f16x8*)((halfp) + 16384 + swz + 12288) = srd;

  STAGE_LOAD(0, 1984 - i0b);
  { char* nh = lds; STAGE_WRITE(nh); }

  const size_t qbase = ((size_t)bh * 2048 + i0 + m) * 64 + g * 8;
  f16x8 qcf0 = *(const f16x8*)(qc + qbase);
  f16x8 qcf1 = *(const f16x8*)(qc + qbase + 32);
  f16x8 qpf0 = *(const f16x8*)(qp + qbase);
  f16x8 qpf1 = *(const f16x8*)(qp + qbase + 32);

  __syncthreads();

  f32x4 acc_o[4] = {};
  float m_run[4], l_run[4];
#pragma unroll
  for (int r = 0; r < 4; ++r) { m_run[r] = -1e30f; l_run[r] = 0.f; }

  const int sx = m & 7;
  const int fo0 = (g ^ sx) << 4;
  const int fo1 = ((4 | g) ^ sx) << 4;
  const int rrow0 = 48 - (w << 4) + m;
  _Float16* Pl = (_Float16*)(lds + 65536 + w * 2304);

  for (int jt = 0; jt < 32; ++jt) {
    if (jt < 31) {
      const int j0n = (jt + 1) << 6;
      STAGE_LOAD(j0n, j0n - i0b + 1984);
    }
    const char* curh = lds + ((jt & 1) << 15);
    f32x4 sc[4] = {};
#pragma unroll
    for (int cf = 0; cf < 4; ++cf) {
      const char* kp = curh + ((m + (cf << 4)) << 7);
      sc[cf] = MFMA16(qcf0, *(const f16x8*)(kp + fo0), sc[cf]);
      sc[cf] = MFMA16(qcf1, *(const f16x8*)(kp + fo1), sc[cf]);
    }
    f32x4 rc[5] = {};
#pragma unroll
    for (int cf = 0; cf < 5; ++cf) {
      const char* rp = curh + 16384 + ((rrow0 + (cf << 4)) << 7);
      rc[cf] = MFMA16(qpf0, *(const f16x8*)(rp + fo0), rc[cf]);
      rc[cf] = MFMA16(qpf1, *(const f16x8*)(rp + fo1), rc[cf]);
    }
#pragma unroll
    for (int r = 0; r < 4; ++r) {
      const int lr = g * 4 + r;
      const int u = 15 + m - lr;
      const int src = (g << 4) | (u & 15);
      const bool hi = (m > lr);
      float sh0 = __shfl(rc[0][r], src);
      float sh1 = __shfl(rc[1][r], src);
      float sh2 = __shfl(rc[2][r], src);
      float sh3 = __shfl(rc[3][r], src);
      float sh4 = __shfl(rc[4][r], src);
      sc[0][r] += hi ? sh1 : sh0;
      sc[1][r] += hi ? sh2 : sh1;
      sc[2][r] += hi ? sh3 : sh2;
      sc[3][r] += hi ? sh4 : sh3;
    }
    float P[4][4];
#pragma unroll
    for (int r = 0; r < 4; ++r) {
      float mx = fmaxf(fmaxf(sc[0][r], sc[1][r]), fmaxf(sc[2][r], sc[3][r]));
      mx = fmaxf(mx, __shfl_xor(mx, 1));
      mx = fmaxf(mx, __shfl_xor(mx, 2));
      mx = fmaxf(mx, __shfl_xor(mx, 4));
      mx = fmaxf(mx, __shfl_xor(mx, 8));
      const float mnew = fmaxf(m_run[r], mx);
      const float corr = __expf(m_run[r] - mnew);
      float rs = 0.f;
#pragma unroll
      for (int cf = 0; cf < 4; ++cf) {
        float p = __expf(sc[cf][r] - mnew);
        P[cf][r] = p;
        rs += p;
      }
      rs += __shfl_xor(rs, 1);
      rs += __shfl_xor(rs, 2);
      rs += __shfl_xor(rs, 4);
      rs += __shfl_xor(rs, 8);
      l_run[r] = l_run[r] * corr + rs;
      m_run[r] = mnew;
#pragma unroll
      for (int cf = 0; cf < 4; ++cf) acc_o[cf][r] *= corr;
    }
#pragma unroll
    for (int cf = 0; cf < 4; ++cf)
#pragma unroll
      for (int r = 0; r < 4; ++r)
        Pl[(g * 4 + r) * 72 + cf * 16 + m] = (_Float16)P[cf][r];
#pragma unroll
    for (int ks = 0; ks < 2; ++ks) {
      f16x8 pa = *(const f16x8*)((const char*)Pl + m * 144 + ks * 64 + (g << 4));
#pragma unroll
      for (int cf = 0; cf < 4; ++cf) {
        const char* vp = curh + 8192 + ((m + (cf << 4)) << 7);
        acc_o[cf] = MFMA16(pa, *(const f16x8*)(vp + (ks ? fo1 : fo0)), acc_o[cf]);
      }
    }
    if (jt < 31) {
      char* nh = lds + (((jt & 1) ^ 1) << 15);
      STAGE_WRITE(nh);
    }
    __syncthreads();
  }
#pragma unroll
  for (int cf = 0; cf < 4; ++cf)
#pragma unroll
    for (int r = 0; r < 4; ++r) {
      const int i = i0 + g * 4 + r;
      const float o = acc_o[cf][r] / l_run[r];
      attnb[((size_t)(b * 2048 + i)) * 512 + h * 64 + cf * 16 + m] = (_Float16)o;
    }
#undef STAGE_LOAD
#undef STAGE_WRITE
}

extern "C" void kernel_launch(void* const* d_in, const int* in_sizes, int n_in,
                              void* d_out, int out_size, void* d_ws, size_t ws_size,
                              hipStream_t stream) {
  (void)in_sizes; (void)n_in; (void)out_size; (void)ws_size;
  const float* x    = (const float*)d_in[0];
  const float* Wq   = (const float*)d_in[1];
  const float* Wk   = (const float*)d_in[2];
  const float* Wv   = (const float*)d_in[3];
  const float* Wrel = (const float*)d_in[4];
  const float* bc   = (const float*)d_in[5];  // rel_content_bias [8*64]
  const float* bp   = (const float*)d_in[6];  // rel_pos_bias [8*64]
  const float* Wo   = (const float*)d_in[7];
  const float* bo   = (const float*)d_in[8];
  float* out = (float*)d_out;

  char* ws = (char*)d_ws;
  size_t off = 0;
  auto alloc = [&](size_t bytes) -> void* {
    void* p = ws + off;
    off += (bytes + 255) & ~(size_t)255;
    return p;
  };
  _Float16* xb     = (_Float16*)alloc(4096ull * 768 * 2);    // x in fp16
  _Float16* wqkvt  = (_Float16*)alloc(1536ull * 768 * 2);    // [Wq;Wk;Wv]^T fp16
  _Float16* wrelt  = (_Float16*)alloc(512ull * 192 * 2);
  _Float16* wot    = (_Float16*)alloc(768ull * 512 * 2);
  _Float16* posb   = (_Float16*)alloc(4096ull * 192 * 2);    // positional features (row 4095 = 0)
  float*    lnrm   = (float*)alloc(32 * 4);                  // gamma log-norm constants
  _Float16* qcb    = (_Float16*)alloc(16ull * 2048 * 64 * 2);   // (q*scale + bc)  [b][h][n][64]
  _Float16* qpb    = (_Float16*)alloc(16ull * 2048 * 64 * 2);   // (q*scale + bp)
  _Float16* kbb    = (_Float16*)alloc(16ull * 2048 * 64 * 2);   // k [b][h][n][64]
  _Float16* vtb    = (_Float16*)alloc(16ull * 64 * 2048 * 2);   // v^T [b][h][64][n]
  _Float16* relkb  = (_Float16*)alloc(8ull * 4096 * 64 * 2);    // rel_k [h][4096][64]
  _Float16* attnb  = (_Float16*)alloc(4096ull * 512 * 2);       // attention output fp16

  cvt4_kernel<<<3072, 256, 0, stream>>>(x, xb, 786432);
  cvt_t3_tile_kernel<<<dim3(16, 24, 3), 256, 0, stream>>>(Wq, Wk, Wv, wqkvt);
  cvt_t_tile_kernel<<<dim3(16, 6), 256, 0, stream>>>(Wrel, wrelt, 192, 512);
  cvt_t_tile_kernel<<<dim3(24, 16), 256, 0, stream>>>(Wo, wot, 512, 768);
  pos_const_kernel<<<1, 64, 0, stream>>>(lnrm);
  pos_embed_kernel<<<1024, 128, 0, stream>>>(posb, lnrm);

  gemm_tile<0><<<dim3(12, 32), 256, 0, stream>>>(xb, wqkvt, 1536, 768,
                                                 qcb, qpb, kbb, vtb, bc, bp, nullptr);
  gemm_tile<3><<<dim3(4, 32), 256, 0, stream>>>(posb, wrelt, 512, 192,
                                                relkb, nullptr, nullptr, nullptr,
                                                nullptr, nullptr, nullptr);

  attn_kernel<<<512, 256, 0, stream>>>(qcb, qpb, kbb, vtb, relkb, attnb);

  gemm_tile<4><<<dim3(6, 32), 256, 0, stream>>>(attnb, wot, 768, 512,
                                                nullptr, nullptr, nullptr, nullptr,
                                                bo, nullptr, out);
}

// Round 8
// 191.529 us; speedup vs baseline: 2.2868x; 1.1147x over previous
//
#include <hip/hip_runtime.h>
#include <hip/hip_bf16.h>
#include <math.h>

// Sizes (fixed): BATCH=2, SEQ=2048, DIM=768, HEADS=8, DK=DV=64, F=192, d_inner=512
// All internal compute in fp16 storage + fp32 MFMA accumulation.

typedef _Float16 f16x8 __attribute__((ext_vector_type(8)));
typedef _Float16 f16x4 __attribute__((ext_vector_type(4)));
typedef float f32x4 __attribute__((ext_vector_type(4)));

#define MFMA16(a, b, c) __builtin_amdgcn_mfma_f32_16x16x32_f16((a), (b), (c), 0, 0, 0)

// async global->LDS, 16B per lane; dest must be (wave-uniform base + lane*16)
#define GL16(gp, lp)                                                       \
  __builtin_amdgcn_global_load_lds(                                        \
      (const __attribute__((address_space(1))) void*)(gp),                 \
      (__attribute__((address_space(3))) void*)(lp), 16, 0, 0)

// 16-lane max-reduce on the VALU pipe (DPP), zero DS-pipe ops.
// xor1, xor2, xor7(row_half_mirror), xor15(row_mirror) covers all 16 lanes.
__device__ __forceinline__ float dpp_fmax16(float x) {
  int v;
  v = __builtin_amdgcn_update_dpp(0, __float_as_int(x), 0xB1, 0xf, 0xf, true);
  x = fmaxf(x, __int_as_float(v));
  v = __builtin_amdgcn_update_dpp(0, __float_as_int(x), 0x4E, 0xf, 0xf, true);
  x = fmaxf(x, __int_as_float(v));
  v = __builtin_amdgcn_update_dpp(0, __float_as_int(x), 0x141, 0xf, 0xf, true);
  x = fmaxf(x, __int_as_float(v));
  v = __builtin_amdgcn_update_dpp(0, __float_as_int(x), 0x140, 0xf, 0xf, true);
  x = fmaxf(x, __int_as_float(v));
  return x;
}

// ---------------- fused prep: x->fp16 | 3 weight transposes | pos embed ----------------
// grid 5216 = 3072 (cvt4) + 1632 (transposes: 1152 qkv + 96 wrel + 384 wo) + 512 (pos, 8 rows ea)
__global__ __launch_bounds__(256) void prep_kernel(
    const float* __restrict__ x, const float* __restrict__ Wq,
    const float* __restrict__ Wk, const float* __restrict__ Wv,
    const float* __restrict__ Wrel, const float* __restrict__ Wo,
    _Float16* __restrict__ xb, _Float16* __restrict__ wqkvt,
    _Float16* __restrict__ wrelt, _Float16* __restrict__ wot,
    _Float16* __restrict__ posb) {
  __shared__ float tile[32][33];
  const int t = threadIdx.x;
  int bid = blockIdx.x;
  if (bid < 3072) {  // x -> fp16, float4-vectorized
    const int idx = bid * 256 + t;
    float4 v = ((const float4*)x)[idx];
    f16x4 o;
    o[0] = (_Float16)v.x; o[1] = (_Float16)v.y; o[2] = (_Float16)v.z; o[3] = (_Float16)v.w;
    ((f16x4*)xb)[idx] = o;
    return;
  }
  bid -= 3072;
  if (bid < 1632) {  // tiled transpose f32 [K][N] -> fp16 [N][K]
    const float* in; _Float16* out; int K_, N_, bx, by;
    if (bid < 1152) {
      const int z = bid / 384, rem = bid % 384;
      in = (z == 0) ? Wq : (z == 1) ? Wk : Wv;
      out = wqkvt + (size_t)z * 512 * 768;
      K_ = 768; N_ = 512; bx = rem & 15; by = rem >> 4;       // 16 x 24
    } else if (bid < 1248) {
      const int rem = bid - 1152;
      in = Wrel; out = wrelt;
      K_ = 192; N_ = 512; bx = rem & 15; by = rem >> 4;       // 16 x 6
    } else {
      const int rem = bid - 1248;
      in = Wo; out = wot;
      K_ = 512; N_ = 768; bx = rem % 24; by = rem / 24;       // 24 x 16
    }
    const int k0 = by * 32, n0 = bx * 32;
    const int tr = t >> 3, tc = (t & 7) * 4;
    float4 v = *(const float4*)(in + (size_t)(k0 + tr) * N_ + n0 + tc);
    tile[tr][tc] = v.x; tile[tr][tc + 1] = v.y; tile[tr][tc + 2] = v.z; tile[tr][tc + 3] = v.w;
    __syncthreads();
    f16x4 o;
    o[0] = (_Float16)tile[tc][tr];
    o[1] = (_Float16)tile[tc + 1][tr];
    o[2] = (_Float16)tile[tc + 2][tr];
    o[3] = (_Float16)tile[tc + 3][tr];
    *(f16x4*)(out + (size_t)(n0 + tr) * K_ + k0 + tc) = o;
    return;
  }
  bid -= 1632;  // positional embedding: 8 rows / block
  const int lr = t >> 5, i = t & 31;
  const int r = bid * 8 + lr;
  _Float16* row = posb + (size_t)r * 192;
  if (r >= 4095) {
    row[i] = (_Float16)0.f; row[32 + i] = (_Float16)0.f; row[64 + i] = (_Float16)0.f;
    row[96 + i] = (_Float16)0.f; row[128 + i] = (_Float16)0.f; row[160 + i] = (_Float16)0.f;
    return;
  }
  const float dist = (float)(r - 2047);
  const float absd = fabsf(dist);
  const float sgn = (dist > 0.f) ? 1.f : ((dist < 0.f) ? -1.f : 0.f);
  const float e = 3.f + (float)i * (8.f / 31.f);
  const float expv = exp2f(-absd * exp2f(-e));
  const float cw = exp2f((float)(i + 1)) - 1.f;
  const float cm = (cw > absd) ? 1.f : 0.f;
  const float mean = 64.f * (float)(i + 1);
  const float conc = (mean / 32.f) * (mean / 32.f);
  const float rate = mean / 1024.f;
  const float lnrm = lgammaf(conc) - conc * logf(rate);
  const float lu = (conc - 1.f) * logf(absd) - rate * absd;
  float gv = expf(lu - lnrm) + 1e-8f;
  float mx = gv;
  mx = fmaxf(mx, __shfl_xor(mx, 1));
  mx = fmaxf(mx, __shfl_xor(mx, 2));
  mx = fmaxf(mx, __shfl_xor(mx, 4));
  mx = fmaxf(mx, __shfl_xor(mx, 8));
  mx = fmaxf(mx, __shfl_xor(mx, 16));
  gv /= mx;
  row[i] = (_Float16)expv;              row[32 + i] = (_Float16)cm;
  row[64 + i] = (_Float16)gv;           row[96 + i] = (_Float16)(sgn * expv);
  row[128 + i] = (_Float16)(sgn * cm);  row[160 + i] = (_Float16)(sgn * gv);
}

// ---------------- LDS-staged MFMA GEMM: C[M][*] = A[M][K] * Bt[N][K]^T ----------------
// 64(M) x 128(N) tile, BK=32, 256 thr = 4 waves (2x2 of 32x64), double-buffered
// swizzled LDS filled via global_load_lds with pre-swizzled source slots.
// MODE 0: qkv fused (N=1536): cols 0..511 -> qc/qp, 512..1023 -> k, 1024..1535 -> vT
// MODE 3: relk -> fp16 [h][4096][64];  MODE 4: out-proj -> f32 [row][N] + bias0[col]
template <int MODE>
__global__ __launch_bounds__(256, 4) void gemm_tile(
    const _Float16* __restrict__ A, const _Float16* __restrict__ Bt,
    const int N, const int K,
    _Float16* __restrict__ o0, _Float16* __restrict__ o1,
    _Float16* __restrict__ o2, _Float16* __restrict__ o3,
    const float* __restrict__ bias0, const float* __restrict__ bias1,
    float* __restrict__ outf) {
  __shared__ __align__(16) _Float16 As[2][64 * 32];    // 4 KB each
  __shared__ __align__(16) _Float16 Bs[2][128 * 32];   // 8 KB each
  const int tid = threadIdx.x;
  const int w = tid >> 6, lane = tid & 63, g = lane >> 4, m = lane & 15;
  const int wr = w >> 1, wc = w & 1;
  const int row0 = blockIdx.y * 64;
  const int c0 = blockIdx.x * 128;

  // A staging: row = tid>>2 (64 rows x 4 slots of 16B); phys slot = tid&3, src slot XOR'd
  const int arow = tid >> 2, asl = tid & 3;
  const int axor = asl ^ ((arow >> 1) & 3);
  const char* Ag = (const char*)(A + (size_t)(row0 + arow) * K) + (axor << 4);
  const int adst = (arow << 6) + (asl << 4);           // = wave_base + lane*16
  // B staging: 2 rows/thread (brow, brow+16)
  const int brow = w * 32 + (lane >> 2);
  const int bxor = asl ^ ((brow >> 1) & 3);            // same for brow+16
  const char* Bg = (const char*)(Bt + (size_t)(c0 + brow) * K) + (bxor << 4);
  const size_t bstep = (size_t)16 * K * 2;
  const int bdst = (brow << 6) + (asl << 4);

  int aoff[2], boff[4];
#pragma unroll
  for (int i = 0; i < 2; ++i) {
    const int ar = wr * 32 + i * 16 + m;
    aoff[i] = (ar << 6) + ((g ^ ((ar >> 1) & 3)) << 4);
  }
#pragma unroll
  for (int i = 0; i < 4; ++i) {
    const int br = wc * 64 + i * 16 + m;
    boff[i] = (br << 6) + ((g ^ ((br >> 1) & 3)) << 4);
  }

#define STAGEG(buf, k0v)                                       \
  GL16(Ag + ((k0v) << 1), (char*)As[buf] + adst);              \
  GL16(Bg + ((k0v) << 1), (char*)Bs[buf] + bdst);              \
  GL16(Bg + bstep + ((k0v) << 1), (char*)Bs[buf] + bdst + 1024);

  f32x4 acc[2][4] = {};
  STAGEG(0, 0);
  __syncthreads();
  const int nk = K >> 5;
  for (int ks = 0; ks < nk; ++ks) {
    const int cur = ks & 1;
    if (ks + 1 < nk) { STAGEG(cur ^ 1, (ks + 1) << 5); }
    const char* ap = (const char*)As[cur];
    const char* bp = (const char*)Bs[cur];
    f16x8 af[2], bf[4];
#pragma unroll
    for (int i = 0; i < 2; ++i) af[i] = *(const f16x8*)(ap + aoff[i]);
#pragma unroll
    for (int i = 0; i < 4; ++i) bf[i] = *(const f16x8*)(bp + boff[i]);
#pragma unroll
    for (int mi = 0; mi < 2; ++mi)
#pragma unroll
      for (int ni = 0; ni < 4; ++ni)
        acc[mi][ni] = MFMA16(af[mi], bf[ni], acc[mi][ni]);
    __syncthreads();
  }
#undef STAGEG

  // ---- epilogue ----
  const int proj = (MODE == 0) ? (c0 >> 9) : 0;
#pragma unroll
  for (int ni = 0; ni < 4; ++ni) {
    const int col = c0 + wc * 64 + ni * 16 + m;
    const int c = col & 511, hh = (MODE == 0) ? (c >> 6) : (col >> 6);
    const int dk = col & 63;
    float b0f = 0.f, b1f = 0.f;
    if (MODE == 0 && proj == 0) { b0f = bias0[c]; b1f = bias1[c]; }
    if (MODE == 0 && proj == 2) {
#pragma unroll
      for (int mi = 0; mi < 2; ++mi) {
        const int rowb = row0 + wr * 32 + mi * 16 + g * 4;
        const int bb = rowb >> 11, n = rowb & 2047;
        f16x4 pk;
#pragma unroll
        for (int r = 0; r < 4; ++r) pk[r] = (_Float16)acc[mi][ni][r];
        *(f16x4*)(o3 + ((size_t)(bb * 8 + hh) * 64 + dk) * 2048 + n) = pk;
      }
    } else {
#pragma unroll
      for (int mi = 0; mi < 2; ++mi) {
#pragma unroll
        for (int r = 0; r < 4; ++r) {
          const int row = row0 + wr * 32 + mi * 16 + g * 4 + r;
          const float v = acc[mi][ni][r];
          if (MODE == 0) {
            const int bb = row >> 11, n = row & 2047;
            const size_t ad = ((size_t)(bb * 8 + hh) * 2048 + n) * 64 + dk;
            if (proj == 0) {
              const float vs = v * 0.125f;  // DIM_KEY^-0.5
              o0[ad] = (_Float16)(vs + b0f);
              o1[ad] = (_Float16)(vs + b1f);
            } else {
              o2[ad] = (_Float16)v;
            }
          } else if (MODE == 3) {
            o0[((size_t)hh * 4096 + row) * 64 + dk] = (_Float16)v;
          } else {
            outf[(size_t)row * N + col] = v + bias0[col];
          }
        }
      }
    }
  }
}

// ---------------- fused rel-pos attention: 4-wave block, gl_lds staging ----------------
// grid 512 x 256 thr. Per 64-wide j-tile: stage K[64][64], V^T[64][64], relk[128][64]
// via global_load_lds (pre-swizzled SOURCE slots, linear dest; physical layout identical
// to the swizzled ds_write layout, so fragment reads are unchanged).
// Softmax: max via DPP (VALU), sum via MFMA with ones-B (matrix pipe). No sum shuffles.
__global__ __launch_bounds__(256, 2) void attn_kernel(
    const _Float16* __restrict__ qc, const _Float16* __restrict__ qp,
    const _Float16* __restrict__ kb, const _Float16* __restrict__ vtb,
    const _Float16* __restrict__ relkb, _Float16* __restrict__ attnb) {
  __shared__ __align__(16) char lds[2 * 32768 + 4 * 2304];  // 2x(K 8K | V 8K | R 16K) + P
  const int tid = threadIdx.x;
  const int w = tid >> 6, lane = tid & 63, g = lane >> 4, m = lane & 15;
  const int L = blockIdx.x;
  const int h = L & 7;
  const int r2 = L >> 3;
  const int b = r2 >> 5, xt = r2 & 31;
  const int bh = b * 8 + h;
  const int i0b = xt << 6;
  const int i0 = i0b + w * 16;

  // staging geometry: srow = tid>>3 (32 rows/pass), 8 slots of 16B per 128B row.
  // phys slot = ssl (linear dest); source slot = ssl ^ (srow&7)  [(srow+32k)&7 invariant]
  const int srow = tid >> 3, ssl = tid & 7;
  const int sxr16 = (ssl ^ (srow & 7)) << 4;
  const int dst16 = (srow << 7) + (ssl << 4);  // = wave_base + lane*16 (linear per wave)
  const char* kgs = (const char*)kb + ((size_t)bh << 18) + sxr16;
  const char* vgs = (const char*)vtb + ((size_t)bh << 18) + ((size_t)srow << 12) + sxr16;
  const char* rgs = (const char*)relkb + ((size_t)h << 19) + sxr16;

#define STAGE(halfp, j0v, d0v)                                                  \
  GL16(kgs + ((size_t)((j0v) + srow) << 7), (halfp) + dst16);                   \
  GL16(kgs + ((size_t)((j0v) + srow + 32) << 7), (halfp) + dst16 + 4096);       \
  GL16(vgs + ((j0v) << 1), (halfp) + 8192 + dst16);                             \
  GL16(vgs + ((size_t)32 << 12) + ((j0v) << 1), (halfp) + 8192 + dst16 + 4096); \
  GL16(rgs + ((size_t)((d0v) + srow) << 7), (halfp) + 16384 + dst16);           \
  GL16(rgs + ((size_t)((d0v) + srow + 32) << 7), (halfp) + 16384 + dst16 + 4096); \
  GL16(rgs + ((size_t)((d0v) + srow + 64) << 7), (halfp) + 16384 + dst16 + 8192); \
  GL16(rgs + ((size_t)((d0v) + srow + 96) << 7), (halfp) + 16384 + dst16 + 12288);

  // prologue: stage tile 0 into buffer 0
  STAGE(lds, 0, 1984 - i0b);

  const size_t qbase = ((size_t)bh * 2048 + i0 + m) * 64 + g * 8;
  f16x8 qcf0 = *(const f16x8*)(qc + qbase);
  f16x8 qcf1 = *(const f16x8*)(qc + qbase + 32);
  f16x8 qpf0 = *(const f16x8*)(qp + qbase);
  f16x8 qpf1 = *(const f16x8*)(qp + qbase + 32);

  f16x8 onesv;
#pragma unroll
  for (int i = 0; i < 8; ++i) onesv[i] = (_Float16)1.f;

  __syncthreads();

  f32x4 acc_o[4] = {};
  f32x4 acc_l = {};
  float m_run[4];
#pragma unroll
  for (int r = 0; r < 4; ++r) m_run[r] = -1e30f;

  const int sx = m & 7;
  const int fo0 = (g ^ sx) << 4;
  const int fo1 = ((4 | g) ^ sx) << 4;
  const int rrow0 = 48 - (w << 4) + m;
  _Float16* Pl = (_Float16*)(lds + 65536 + w * 2304);  // per-wave [16][72]

  for (int jt = 0; jt < 32; ++jt) {
    if (jt < 31) {
      const int j0n = (jt + 1) << 6;
      char* nh = lds + (((jt & 1) ^ 1) << 15);
      STAGE(nh, j0n, j0n - i0b + 1984);
    }
    const char* curh = lds + ((jt & 1) << 15);
    // ---- content logits S_c [16 x 64] ----
    f32x4 sc[4] = {};
#pragma unroll
    for (int cf = 0; cf < 4; ++cf) {
      const char* kp = curh + ((m + (cf << 4)) << 7);
      sc[cf] = MFMA16(qcf0, *(const f16x8*)(kp + fo0), sc[cf]);
      sc[cf] = MFMA16(qcf1, *(const f16x8*)(kp + fo1), sc[cf]);
    }
    // ---- rel logits band R [16 x 80] ----
    f32x4 rc[5] = {};
#pragma unroll
    for (int cf = 0; cf < 5; ++cf) {
      const char* rp = curh + 16384 + ((rrow0 + (cf << 4)) << 7);
      rc[cf] = MFMA16(qpf0, *(const f16x8*)(rp + fo0), rc[cf]);
      rc[cf] = MFMA16(qpf1, *(const f16x8*)(rp + fo1), rc[cf]);
    }
    // ---- in-register shift gather + add ----
#pragma unroll
    for (int r = 0; r < 4; ++r) {
      const int lr = g * 4 + r;
      const int u = 15 + m - lr;
      const int src = (g << 4) | (u & 15);
      const bool hi = (m > lr);
      float sh0 = __shfl(rc[0][r], src);
      float sh1 = __shfl(rc[1][r], src);
      float sh2 = __shfl(rc[2][r], src);
      float sh3 = __shfl(rc[3][r], src);
      float sh4 = __shfl(rc[4][r], src);
      sc[0][r] += hi ? sh1 : sh0;
      sc[1][r] += hi ? sh2 : sh1;
      sc[2][r] += hi ? sh3 : sh2;
      sc[3][r] += hi ? sh4 : sh3;
    }
    // ---- online softmax: max via DPP (VALU); sum via MFMA-ones below ----
    float P[4][4];
#pragma unroll
    for (int r = 0; r < 4; ++r) {
      float mx = fmaxf(fmaxf(sc[0][r], sc[1][r]), fmaxf(sc[2][r], sc[3][r]));
      mx = dpp_fmax16(mx);
      const float mnew = fmaxf(m_run[r], mx);
      const float corr = __expf(m_run[r] - mnew);
      m_run[r] = mnew;
#pragma unroll
      for (int cf = 0; cf < 4; ++cf) {
        P[cf][r] = __expf(sc[cf][r] - mnew);
        acc_o[cf][r] *= corr;
      }
      acc_l[r] *= corr;
    }
    // ---- P -> fp16 -> wave-private LDS (same-wave DS ordering, no barrier) ----
#pragma unroll
    for (int cf = 0; cf < 4; ++cf)
#pragma unroll
      for (int r = 0; r < 4; ++r)
        Pl[(g * 4 + r) * 72 + cf * 16 + m] = (_Float16)P[cf][r];
    // ---- PV + row-sum: acc_o += P.V ; acc_l += P.1 ----
#pragma unroll
    for (int ks = 0; ks < 2; ++ks) {
      f16x8 pa = *(const f16x8*)((const char*)Pl + m * 144 + ks * 64 + (g << 4));
#pragma unroll
      for (int cf = 0; cf < 4; ++cf) {
        const char* vp = curh + 8192 + ((m + (cf << 4)) << 7);
        acc_o[cf] = MFMA16(pa, *(const f16x8*)(vp + (ks ? fo1 : fo0)), acc_o[cf]);
      }
      acc_l = MFMA16(pa, onesv, acc_l);
    }
    __syncthreads();
  }
  // ---- epilogue: normalize, write attn output [b][n][h*64+dv] fp16 ----
#pragma unroll
  for (int cf = 0; cf < 4; ++cf)
#pragma unroll
    for (int r = 0; r < 4; ++r) {
      const int i = i0 + g * 4 + r;
      const float o = acc_o[cf][r] / acc_l[r];
      attnb[((size_t)(b * 2048 + i)) * 512 + h * 64 + cf * 16 + m] = (_Float16)o;
    }
#undef STAGE
}

extern "C" void kernel_launch(void* const* d_in, const int* in_sizes, int n_in,
                              void* d_out, int out_size, void* d_ws, size_t ws_size,
                              hipStream_t stream) {
  (void)in_sizes; (void)n_in; (void)out_size; (void)ws_size;
  const float* x    = (const float*)d_in[0];
  const float* Wq   = (const float*)d_in[1];
  const float* Wk   = (const float*)d_in[2];
  const float* Wv   = (const float*)d_in[3];
  const float* Wrel = (const float*)d_in[4];
  const float* bc   = (const float*)d_in[5];  // rel_content_bias [8*64]
  const float* bp   = (const float*)d_in[6];  // rel_pos_bias [8*64]
  const float* Wo   = (const float*)d_in[7];
  const float* bo   = (const float*)d_in[8];
  float* out = (float*)d_out;

  char* ws = (char*)d_ws;
  size_t off = 0;
  auto alloc = [&](size_t bytes) -> void* {
    void* p = ws + off;
    off += (bytes + 255) & ~(size_t)255;
    return p;
  };
  _Float16* xb     = (_Float16*)alloc(4096ull * 768 * 2);    // x in fp16
  _Float16* wqkvt  = (_Float16*)alloc(1536ull * 768 * 2);    // [Wq;Wk;Wv]^T fp16
  _Float16* wrelt  = (_Float16*)alloc(512ull * 192 * 2);
  _Float16* wot    = (_Float16*)alloc(768ull * 512 * 2);
  _Float16* posb   = (_Float16*)alloc(4096ull * 192 * 2);    // positional features (row 4095 = 0)
  _Float16* qcb    = (_Float16*)alloc(16ull * 2048 * 64 * 2);   // (q*scale + bc)  [b][h][n][64]
  _Float16* qpb    = (_Float16*)alloc(16ull * 2048 * 64 * 2);   // (q*scale + bp)
  _Float16* kbb    = (_Float16*)alloc(16ull * 2048 * 64 * 2);   // k [b][h][n][64]
  _Float16* vtb    = (_Float16*)alloc(16ull * 64 * 2048 * 2);   // v^T [b][h][64][n]
  _Float16* relkb  = (_Float16*)alloc(8ull * 4096 * 64 * 2);    // rel_k [h][4096][64]
  _Float16* attnb  = (_Float16*)alloc(4096ull * 512 * 2);       // attention output fp16

  prep_kernel<<<5216, 256, 0, stream>>>(x, Wq, Wk, Wv, Wrel, Wo,
                                        xb, wqkvt, wrelt, wot, posb);

  gemm_tile<0><<<dim3(12, 64), 256, 0, stream>>>(xb, wqkvt, 1536, 768,
                                                 qcb, qpb, kbb, vtb, bc, bp, nullptr);
  gemm_tile<3><<<dim3(4, 64), 256, 0, stream>>>(posb, wrelt, 512, 192,
                                                relkb, nullptr, nullptr, nullptr,
                                                nullptr, nullptr, nullptr);

  attn_kernel<<<512, 256, 0, stream>>>(qcb, qpb, kbb, vtb, relkb, attnb);

  gemm_tile<4><<<dim3(6, 64), 256, 0, stream>>>(attnb, wot, 768, 512,
                                                nullptr, nullptr, nullptr, nullptr,
                                                bo, nullptr, out);
}